// Round 10
// baseline (1453.219 us; speedup 1.0000x reference)
//
#include <hip/hip_runtime.h>

// Problem constants (match reference)
#define NN 50000     // nodes
#define NE 400000    // edges
#define NG 128       // graphs
#define DIM 256      // hidden
#define NL 3         // layers
#define OUTF 128
#define GN_EPS 1e-5f

typedef __attribute__((ext_vector_type(8))) __bf16 bf16x8;
typedef __attribute__((ext_vector_type(8))) unsigned short us8;
typedef __attribute__((ext_vector_type(4))) unsigned short us4;
typedef __attribute__((ext_vector_type(4))) float f32x4;

static __device__ __forceinline__ unsigned short f2bf(float f) {
  unsigned int u = __float_as_uint(f);
  unsigned int r = (u + 0x7fffu + ((u >> 16) & 1u)) >> 16;
  return (unsigned short)r;
}
static __device__ __forceinline__ float bf2f(unsigned short h) {
  return __uint_as_float(((unsigned int)h) << 16);
}
static __device__ __forceinline__ float fast_tanh(float x) {
  x = fminf(fmaxf(x, -15.f), 15.f);
  float e = __expf(2.f * x);
  return __fdividef(e - 1.f, e + 1.f);
}

// ---------------------------------------------------------------------------
__global__ __launch_bounds__(256) void k_encoder(
    const float* __restrict__ x, const float* __restrict__ w,
    const float* __restrict__ b, float* __restrict__ h) {
  int n = blockIdx.x, c = threadIdx.x;
  float x0 = x[n * 3 + 0], x1 = x[n * 3 + 1], x2 = x[n * 3 + 2];
  h[n * DIM + c] = b[c] + x0 * w[c] + x1 * w[DIM + c] + x2 * w[2 * DIM + c];
}

// ---------------------------------------------------------------------------
// CSR build
__global__ __launch_bounds__(256) void k_hist(const int* __restrict__ ei,
                                              int* __restrict__ cnt) {
  int e = blockIdx.x * 256 + threadIdx.x;
  if (e < NE) atomicAdd(&cnt[ei[NE + e]], 1);
}

__global__ __launch_bounds__(1024) void k_scan(const int* __restrict__ cnt,
                                               int* __restrict__ rowptr,
                                               int* __restrict__ cur) {
  __shared__ int ssum[1024];
  int t = threadIdx.x;
  const int CH = (NN + 1023) / 1024;
  int beg = t * CH, end = beg + CH;
  if (end > NN) end = NN;
  int s = 0;
  for (int i = beg; i < end; ++i) s += cnt[i];
  ssum[t] = s;
  __syncthreads();
  for (int off = 1; off < 1024; off <<= 1) {
    int v = (t >= off) ? ssum[t - off] : 0;
    __syncthreads();
    ssum[t] += v;
    __syncthreads();
  }
  int run = ssum[t] - s;
  for (int i = beg; i < end; ++i) {
    rowptr[i] = run;
    cur[i] = run;
    run += cnt[i];
  }
  if (t == 1023) rowptr[NN] = run;
}

__global__ __launch_bounds__(256) void k_scatter(
    const int* __restrict__ ei, const float4* __restrict__ ea,
    int* __restrict__ cur, int* __restrict__ csr_src,
    float4* __restrict__ csr_ea) {
  int e = blockIdx.x * 256 + threadIdx.x;
  if (e >= NE) return;
  int s = ei[e], d = ei[NE + e];
  int p = atomicAdd(&cur[d], 1);
  csr_src[p] = s;
  csr_ea[p] = ea[e];
}

__global__ __launch_bounds__(256) void k_gstart(const int* __restrict__ batch,
                                                int* __restrict__ gstart) {
  int n = blockIdx.x * 256 + threadIdx.x;
  if (n >= NN) return;
  int b = batch[n];
  int bp = (n == 0) ? -1 : batch[n - 1];
  for (int g = bp + 1; g <= b; ++g) gstart[g] = n;
  if (n == NN - 1)
    for (int g = b + 1; g <= NG; ++g) gstart[g] = NN;
}

// ---------------------------------------------------------------------------
// Weight prep: fp32 [K=256][N=256] -> MFMA B-fragment-ordered bf16 hi/lo.
// Fragment (nt*8+ks): lane l, elem j -> B[k][col], col=(nt<<4)+(l&15),
// k = ks*32 + 4*(l>>4) + 16*(j>>2) + (j&3)
__global__ __launch_bounds__(64) void k_prepw(const float* __restrict__ W,
                                              unsigned short* __restrict__ hi,
                                              unsigned short* __restrict__ lo) {
  int bt = blockIdx.x;  // nt*8 + ks
  int l = threadIdx.x;
  int col = ((bt >> 3) << 4) + (l & 15);
  int kb = ((bt & 7) << 5) + ((l >> 4) << 2);
  int base = (bt * 64 + l) * 8;
#pragma unroll
  for (int j = 0; j < 8; ++j) {
    int k = kb + ((j >> 2) << 4) + (j & 3);
    float w = W[k * DIM + col];
    unsigned short h = f2bf(w);
    hi[base + j] = h;
    lo[base + j] = f2bf(w - bf2f(h));
  }
}

// ---------------------------------------------------------------------------
// GINE aggregation, wave-per-node, 8-deep gather pipeline.
static __device__ __forceinline__ void edge_acc(
    float4& acc, float4 hv, float4 a, float4 wr0, float4 wr1, float4 wr2,
    float4 wr3, float4 bb) {
  float ex = fmaf(a.w, wr3.x, fmaf(a.z, wr2.x, fmaf(a.y, wr1.x, fmaf(a.x, wr0.x, bb.x))));
  float ey = fmaf(a.w, wr3.y, fmaf(a.z, wr2.y, fmaf(a.y, wr1.y, fmaf(a.x, wr0.y, bb.y))));
  float ez = fmaf(a.w, wr3.z, fmaf(a.z, wr2.z, fmaf(a.y, wr1.z, fmaf(a.x, wr0.z, bb.z))));
  float ew_ = fmaf(a.w, wr3.w, fmaf(a.z, wr2.w, fmaf(a.y, wr1.w, fmaf(a.x, wr0.w, bb.w))));
  acc.x += fmaxf(hv.x + ex, 0.f);
  acc.y += fmaxf(hv.y + ey, 0.f);
  acc.z += fmaxf(hv.z + ez, 0.f);
  acc.w += fmaxf(hv.w + ew_, 0.f);
}

__global__ __launch_bounds__(256) void k_aggregate(
    const float4* __restrict__ h4, const int* __restrict__ rowptr,
    const int* __restrict__ csr_src, const float4* __restrict__ csr_ea,
    const float* __restrict__ ew, const float* __restrict__ eb,
    float4* __restrict__ agg4) {
  const int lane = threadIdx.x & 63;
  const int n = (blockIdx.x << 2) + (threadIdx.x >> 6);
  if (n >= NN) return;
  const int c0 = lane << 2;
  const float4 wr0 = *(const float4*)(ew + c0);
  const float4 wr1 = *(const float4*)(ew + DIM + c0);
  const float4 wr2 = *(const float4*)(ew + 2 * DIM + c0);
  const float4 wr3 = *(const float4*)(ew + 3 * DIM + c0);
  const float4 bb = *(const float4*)(eb + c0);
  float4 acc = make_float4(0.f, 0.f, 0.f, 0.f);
  int j = rowptr[n];
  const int j1 = rowptr[n + 1];
  for (; j + 8 <= j1; j += 8) {
    int s[8];
    float4 a[8], hv[8];
#pragma unroll
    for (int u = 0; u < 8; ++u) s[u] = csr_src[j + u];
#pragma unroll
    for (int u = 0; u < 8; ++u) a[u] = csr_ea[j + u];
#pragma unroll
    for (int u = 0; u < 8; ++u) hv[u] = h4[(size_t)s[u] * 64 + lane];
#pragma unroll
    for (int u = 0; u < 8; ++u) edge_acc(acc, hv[u], a[u], wr0, wr1, wr2, wr3, bb);
  }
  for (; j + 2 <= j1; j += 2) {
    int s0 = csr_src[j], s1 = csr_src[j + 1];
    float4 a0 = csr_ea[j], a1 = csr_ea[j + 1];
    float4 h0 = h4[(size_t)s0 * 64 + lane];
    float4 h1 = h4[(size_t)s1 * 64 + lane];
    edge_acc(acc, h0, a0, wr0, wr1, wr2, wr3, bb);
    edge_acc(acc, h1, a1, wr0, wr1, wr2, wr3, bb);
  }
  for (; j < j1; ++j) {
    int s = csr_src[j];
    float4 a = csr_ea[j];
    float4 hv = h4[(size_t)s * 64 + lane];
    edge_acc(acc, hv, a, wr0, wr1, wr2, wr3, bb);
  }
  agg4[(size_t)n * 64 + lane] = acc;
}

// ---------------------------------------------------------------------------
// Register-resident B: wave owns 2 nt-tiles (32 cols). 128 VGPRs.
static __device__ __forceinline__ void load_B(
    const us8* __restrict__ wh, const us8* __restrict__ wl, int w, int lane,
    us8 bh[8][2], us8 bl[8][2]) {
#pragma unroll
  for (int ks = 0; ks < 8; ++ks) {
#pragma unroll
    for (int t = 0; t < 2; ++t) {
      int nt = (w << 1) + t;
      bh[ks][t] = wh[((nt << 3) + ks) * 64 + lane];
      bl[ks][t] = wl[((nt << 3) + ks) * 64 + lane];
    }
  }
}

// GEMM core: wave m-loops over all 4 row-tiles of the 64-row LDS A tile
// (bf16 hi/lo, XOR-swizzled row-major), B register-resident.
// acc[m][t] = C[m*16 + 4*(lane>>4) + q][((w*2+t)*16) + (lane&15)]
static __device__ __forceinline__ void gemm_core(
    const unsigned short* zh, const unsigned short* zl, const us8 bh[8][2],
    const us8 bl[8][2], int lane, f32x4 acc[4][2]) {
#pragma unroll
  for (int m = 0; m < 4; ++m) {
    const int arow = (m << 4) + (lane & 15);
    const int rx = arow & 7;
    const int rbase = arow << 8;
#pragma unroll
    for (int ks = 0; ks < 8; ++ks) {
      int c0 = (ks << 5) + ((lane >> 4) << 2);
      int c1 = c0 + 16;
      int i0 = rbase + ((((c0 >> 3) ^ rx) << 3) | (c0 & 7));
      int i1 = rbase + ((((c1 >> 3) ^ rx) << 3) | (c1 & 7));
      us4 h0 = *(const us4*)(zh + i0), h1 = *(const us4*)(zh + i1);
      us4 l0 = *(const us4*)(zl + i0), l1 = *(const us4*)(zl + i1);
      us8 ahu = {h0.x, h0.y, h0.z, h0.w, h1.x, h1.y, h1.z, h1.w};
      us8 alu = {l0.x, l0.y, l0.z, l0.w, l1.x, l1.y, l1.z, l1.w};
      bf16x8 ah = __builtin_bit_cast(bf16x8, ahu);
      bf16x8 al = __builtin_bit_cast(bf16x8, alu);
#pragma unroll
      for (int t = 0; t < 2; ++t) {
        bf16x8 Bh = __builtin_bit_cast(bf16x8, bh[ks][t]);
        bf16x8 Bl = __builtin_bit_cast(bf16x8, bl[ks][t]);
        acc[m][t] = __builtin_amdgcn_mfma_f32_16x16x32_bf16(ah, Bh, acc[m][t], 0, 0, 0);
        acc[m][t] = __builtin_amdgcn_mfma_f32_16x16x32_bf16(al, Bh, acc[m][t], 0, 0, 0);
        acc[m][t] = __builtin_amdgcn_mfma_f32_16x16x32_bf16(ah, Bl, acc[m][t], 0, 0, 0);
      }
    }
  }
}

// ---------------------------------------------------------------------------
// Fused MLP via MFMA, 512 threads (8 waves), 64-row tile.
// __launch_bounds__(512, 2): min 2 waves/EU -> <=256 VGPR budget. At the
// default the compiler capped at 128 VGPRs and spilled the 128-reg B array
// to scratch (round-5: 900 MB/dispatch HBM spill traffic in k_jk_scores).
__global__ __launch_bounds__(512, 2) void k_mlp(
    const float* __restrict__ h, const float* __restrict__ agg,
    const us8* __restrict__ w1h, const us8* __restrict__ w1l,
    const float* __restrict__ b1,
    const us8* __restrict__ w2h, const us8* __restrict__ w2l,
    const float* __restrict__ b2, float* __restrict__ z2out) {
  __shared__ unsigned short zh[64 * 256];
  __shared__ unsigned short zl[64 * 256];
  const int tid = threadIdx.x;
  const int m0 = blockIdx.x << 6;
  const int w = tid >> 6, lane = tid & 63;
  const int cl = lane & 15;

  us8 bh[8][2], bl[8][2];
  load_B(w1h, w1l, w, lane, bh, bl);

  // stage z = h + agg -> bf16 hi/lo, swizzled
  for (int i = tid; i < 4096; i += 512) {
    int r = i >> 6, c4 = i & 63;
    int n = m0 + r;
    float4 hv = make_float4(0.f, 0.f, 0.f, 0.f), av = hv;
    if (n < NN) {
      hv = *(const float4*)(h + (size_t)n * DIM + (c4 << 2));
      av = *(const float4*)(agg + (size_t)n * DIM + (c4 << 2));
    }
    float z0 = hv.x + av.x, z1 = hv.y + av.y, z2 = hv.z + av.z, z3 = hv.w + av.w;
    unsigned short h0 = f2bf(z0), h1 = f2bf(z1), h2 = f2bf(z2), h3 = f2bf(z3);
    us4 hq = {h0, h1, h2, h3};
    us4 lq = {f2bf(z0 - bf2f(h0)), f2bf(z1 - bf2f(h1)),
              f2bf(z2 - bf2f(h2)), f2bf(z3 - bf2f(h3))};
    int g = (c4 >> 1) ^ (r & 7);
    int idx = (r << 8) + (g << 3) + ((c4 & 1) << 2);
    *(us4*)(zh + idx) = hq;
    *(us4*)(zl + idx) = lq;
  }
  __syncthreads();

  f32x4 acc[4][2];
#pragma unroll
  for (int m = 0; m < 4; ++m) { acc[m][0] = {0.f,0.f,0.f,0.f}; acc[m][1] = {0.f,0.f,0.f,0.f}; }
  gemm_core(zh, zl, bh, bl, lane, acc);

  float bv1[2] = {b1[((w << 1) + 0) * 16 + cl], b1[((w << 1) + 1) * 16 + cl]};
  __syncthreads();  // all pass-1 reads of zh/zl done
#pragma unroll
  for (int m = 0; m < 4; ++m) {
#pragma unroll
    for (int t = 0; t < 2; ++t) {
      int col = ((w << 1) + t) * 16 + cl;
#pragma unroll
      for (int q = 0; q < 4; ++q) {
        float v = fmaxf(acc[m][t][q] + bv1[t], 0.f);
        unsigned short th = f2bf(v);
        unsigned short tl = f2bf(v - bf2f(th));
        int row = (m << 4) + ((lane >> 4) << 2) + q;
        int idx = (row << 8) + ((((col >> 3) ^ (row & 7)) << 3) | (col & 7));
        zh[idx] = th;
        zl[idx] = tl;
      }
    }
  }
  load_B(w2h, w2l, w, lane, bh, bl);  // B1 dead; reuse regs
  __syncthreads();

#pragma unroll
  for (int m = 0; m < 4; ++m) { acc[m][0] = {0.f,0.f,0.f,0.f}; acc[m][1] = {0.f,0.f,0.f,0.f}; }
  gemm_core(zh, zl, bh, bl, lane, acc);

  float bv2[2] = {b2[((w << 1) + 0) * 16 + cl], b2[((w << 1) + 1) * 16 + cl]};
#pragma unroll
  for (int m = 0; m < 4; ++m) {
#pragma unroll
    for (int t = 0; t < 2; ++t) {
      int col = ((w << 1) + t) * 16 + cl;
#pragma unroll
      for (int q = 0; q < 4; ++q) {
        int n = m0 + (m << 4) + ((lane >> 4) << 2) + q;
        if (n < NN)
          z2out[(size_t)n * DIM + col] = fmaxf(acc[m][t][q] + bv2[t], 0.f);
      }
    }
  }
}

// ---------------------------------------------------------------------------
// GraphNorm stats
__global__ __launch_bounds__(256) void k_gnstats(
    const float* __restrict__ z2, const int* __restrict__ gstart,
    const float* __restrict__ gms, float* __restrict__ meanb,
    float* __restrict__ rstdb) {
  __shared__ float red[4][64];
  int g = blockIdx.x;
  int cc = threadIdx.x & 63;
  int c = (blockIdx.y << 6) + cc;
  int ty = threadIdx.x >> 6;
  int s0 = gstart[g], s1 = gstart[g + 1];
  float cntf = fmaxf((float)(s1 - s0), 1.f);
  float s = 0.f;
  for (int n = s0 + ty; n < s1; n += 4) s += z2[(size_t)n * DIM + c];
  red[ty][cc] = s;
  __syncthreads();
  float mean = (red[0][cc] + red[1][cc] + red[2][cc] + red[3][cc]) / cntf;
  float a = mean * gms[c];
  float v = 0.f;
  for (int n = s0 + ty; n < s1; n += 4) {
    float d = z2[(size_t)n * DIM + c] - a;
    v = fmaf(d, d, v);
  }
  __syncthreads();
  red[ty][cc] = v;
  __syncthreads();
  if (ty == 0) {
    float var = (red[0][cc] + red[1][cc] + red[2][cc] + red[3][cc]) / cntf;
    meanb[(size_t)g * DIM + c] = mean;
    rstdb[(size_t)g * DIM + c] = rsqrtf(var + GN_EPS);
  }
}

__global__ __launch_bounds__(256) void k_gnapply(
    const float* __restrict__ z2, const float* __restrict__ hprev,
    const int* __restrict__ batch, const float* __restrict__ meanb,
    const float* __restrict__ rstdb, const float* __restrict__ gms,
    const float* __restrict__ gw, const float* __restrict__ gb,
    float* __restrict__ hout) {
  int n = blockIdx.x, c = threadIdx.x;
  int g = batch[n];
  float mean = meanb[g * DIM + c], rstd = rstdb[g * DIM + c];
  float sub = z2[n * DIM + c] - mean * gms[c];
  hout[n * DIM + c] = fmaf(gw[c] * sub, rstd, gb[c]) + hprev[n * DIM + c];
}

// ---------------------------------------------------------------------------
// JK scores, 512 threads; B register-resident, loops over the 3 layers.
__global__ __launch_bounds__(512, 2) void k_jk_scores(
    const float* __restrict__ lo0, const float* __restrict__ lo1,
    const float* __restrict__ lo2, const us8* __restrict__ wah,
    const us8* __restrict__ wal, const float* __restrict__ ab1,
    const float* __restrict__ aw2, float* __restrict__ scores) {
  __shared__ unsigned short zh[64 * 256];
  __shared__ unsigned short zl[64 * 256];
  __shared__ float sred[8][64];
  const int tid = threadIdx.x;
  const int m0 = blockIdx.x << 6;
  const int w = tid >> 6, lane = tid & 63;
  const int cl = lane & 15;

  us8 bh[8][2], bl[8][2];
  load_B(wah, wal, w, lane, bh, bl);
  float abv[2] = {ab1[((w << 1) + 0) * 16 + cl], ab1[((w << 1) + 1) * 16 + cl]};
  float awv[2] = {aw2[((w << 1) + 0) * 16 + cl], aw2[((w << 1) + 1) * 16 + cl]};

  const float* srcs[NL] = {lo0, lo1, lo2};
  for (int li = 0; li < NL; ++li) {
    const float* src = srcs[li];
    __syncthreads();  // previous iteration's reads done
    for (int i = tid; i < 4096; i += 512) {
      int r = i >> 6, c4 = i & 63;
      int n = m0 + r;
      float4 v = make_float4(0.f, 0.f, 0.f, 0.f);
      if (n < NN) v = *(const float4*)(src + (size_t)n * DIM + (c4 << 2));
      unsigned short h0 = f2bf(v.x), h1 = f2bf(v.y), h2 = f2bf(v.z), h3 = f2bf(v.w);
      us4 hq = {h0, h1, h2, h3};
      us4 lq = {f2bf(v.x - bf2f(h0)), f2bf(v.y - bf2f(h1)),
                f2bf(v.z - bf2f(h2)), f2bf(v.w - bf2f(h3))};
      int g = (c4 >> 1) ^ (r & 7);
      int idx = (r << 8) + (g << 3) + ((c4 & 1) << 2);
      *(us4*)(zh + idx) = hq;
      *(us4*)(zl + idx) = lq;
    }
    __syncthreads();

    f32x4 acc[4][2];
#pragma unroll
    for (int m = 0; m < 4; ++m) { acc[m][0] = {0.f,0.f,0.f,0.f}; acc[m][1] = {0.f,0.f,0.f,0.f}; }
    gemm_core(zh, zl, bh, bl, lane, acc);

    // per-row reduce: sum over this wave's 32 cols, then across waves via LDS
#pragma unroll
    for (int m = 0; m < 4; ++m) {
#pragma unroll
      for (int q = 0; q < 4; ++q) {
        float p = fast_tanh(acc[m][0][q] + abv[0]) * awv[0] +
                  fast_tanh(acc[m][1][q] + abv[1]) * awv[1];
        p += __shfl_xor(p, 1);
        p += __shfl_xor(p, 2);
        p += __shfl_xor(p, 4);
        p += __shfl_xor(p, 8);
        if (cl == 0) sred[w][(m << 4) + ((lane >> 4) << 2) + q] = p;
      }
    }
    __syncthreads();
    if (tid < 64) {
      float s = 0.f;
#pragma unroll
      for (int ww = 0; ww < 8; ++ww) s += sred[ww][tid];
      int n = m0 + tid;
      if (n < NN) scores[(size_t)n * NL + li] = s;
    }
  }
}

// JK softmax + weighted sum + global_add_pool
__global__ __launch_bounds__(256) void k_jk_pool(
    const float* __restrict__ lo0, const float* __restrict__ lo1,
    const float* __restrict__ lo2, const float* __restrict__ scores,
    const int* __restrict__ batch, float* __restrict__ pooled) {
  int m0 = blockIdx.x * 32, c = threadIdx.x;
  float acc = 0.f;
  int curg = -1;
  for (int r = 0; r < 32; ++r) {
    int n = m0 + r;
    if (n >= NN) break;
    int g = batch[n];
    if (g != curg) {
      if (curg >= 0) atomicAdd(&pooled[curg * DIM + c], acc);
      curg = g;
      acc = 0.f;
    }
    float s0 = scores[n * NL], s1 = scores[n * NL + 1], s2 = scores[n * NL + 2];
    float m = fmaxf(s0, fmaxf(s1, s2));
    float e0 = expf(s0 - m), e1 = expf(s1 - m), e2 = expf(s2 - m);
    float inv = 1.f / (e0 + e1 + e2);
    acc += (e0 * lo0[n * DIM + c] + e1 * lo1[n * DIM + c] +
            e2 * lo2[n * DIM + c]) * inv;
  }
  if (curg >= 0) atomicAdd(&pooled[curg * DIM + c], acc);
}

__global__ __launch_bounds__(128) void k_final(
    const float* __restrict__ pooled, const float* __restrict__ fw,
    const float* __restrict__ fb, float* __restrict__ out) {
  int g = blockIdx.x, o = threadIdx.x;
  float acc = fb[o];
  for (int k = 0; k < DIM; ++k)
    acc = fmaf(pooled[g * DIM + k], fw[k * OUTF + o], acc);
  out[g * OUTF + o] = acc;
}

// ---------------------------------------------------------------------------
extern "C" void kernel_launch(void* const* d_in, const int* in_sizes, int n_in,
                              void* d_out, int out_size, void* d_ws,
                              size_t ws_size, hipStream_t stream) {
  const float* x       = (const float*)d_in[0];
  const int*   ei      = (const int*)d_in[1];
  const float* eattr   = (const float*)d_in[2];
  const int*   batch   = (const int*)d_in[3];
  const float* enc_w   = (const float*)d_in[4];
  const float* enc_b   = (const float*)d_in[5];
  const float* edge_w  = (const float*)d_in[6];
  const float* edge_b  = (const float*)d_in[7];
  const float* w1      = (const float*)d_in[8];
  const float* b1      = (const float*)d_in[9];
  const float* w2      = (const float*)d_in[10];
  const float* b2      = (const float*)d_in[11];
  const float* gn_w    = (const float*)d_in[12];
  const float* gn_b    = (const float*)d_in[13];
  const float* gn_ms   = (const float*)d_in[14];
  const float* attn_w1 = (const float*)d_in[15];
  const float* attn_b1 = (const float*)d_in[16];
  const float* attn_w2 = (const float*)d_in[17];
  const float* fc_w    = (const float*)d_in[18];
  const float* fc_b    = (const float*)d_in[19];
  float* out = (float*)d_out;

  char* wsp = (char*)d_ws;
  auto alloc = [&](size_t bytes) {
    void* p = (void*)wsp;
    wsp += (bytes + 255) & ~(size_t)255;
    return p;
  };
  const size_t ND = (size_t)NN * DIM;
  const size_t WSZ = (size_t)DIM * DIM;
  float* henc   = (float*)alloc(ND * 4);
  float* lo0    = (float*)alloc(ND * 4);
  float* lo1    = (float*)alloc(ND * 4);
  float* lo2    = (float*)alloc(ND * 4);
  float* agg    = (float*)alloc(ND * 4);  // reused as z2 (row-safe alias)
  float* meanb  = (float*)alloc((size_t)NG * DIM * 4);
  float* rstdb  = (float*)alloc((size_t)NG * DIM * 4);
  float* scores = (float*)alloc((size_t)NN * NL * 4);
  float* pooled = (float*)alloc((size_t)NG * DIM * 4);
  int* rowptr   = (int*)alloc((size_t)(NN + 1) * 4);
  int* cur      = (int*)alloc((size_t)NN * 4);
  int* cnt      = (int*)alloc((size_t)NN * 4);
  int* gstart   = (int*)alloc((size_t)(NG + 1) * 4);
  int* csr_src  = (int*)alloc((size_t)NE * 4);
  float4* csr_ea = (float4*)alloc((size_t)NE * 16);
  unsigned short* wbh = (unsigned short*)alloc(7 * WSZ * 2);
  unsigned short* wbl = (unsigned short*)alloc(7 * WSZ * 2);

  float* z2 = agg;

  hipMemsetAsync(cnt, 0, (size_t)NN * 4, stream);
  hipMemsetAsync(pooled, 0, (size_t)NG * DIM * 4, stream);

  const int EB = (NE + 255) / 256;
  const int NB = (NN + 255) / 256;
  const int RB64 = (NN + 63) / 64;

  k_encoder<<<NN, 256, 0, stream>>>(x, enc_w, enc_b, henc);
  k_hist<<<EB, 256, 0, stream>>>(ei, cnt);
  k_scan<<<1, 1024, 0, stream>>>(cnt, rowptr, cur);
  k_scatter<<<EB, 256, 0, stream>>>(ei, (const float4*)eattr, cur, csr_src, csr_ea);
  k_gstart<<<NB, 256, 0, stream>>>(batch, gstart);

  for (int i = 0; i < NL; ++i) {
    k_prepw<<<128, 64, 0, stream>>>(w1 + i * WSZ, wbh + i * WSZ, wbl + i * WSZ);
    k_prepw<<<128, 64, 0, stream>>>(w2 + i * WSZ, wbh + (3 + i) * WSZ,
                                    wbl + (3 + i) * WSZ);
  }
  k_prepw<<<128, 64, 0, stream>>>(attn_w1, wbh + 6 * WSZ, wbl + 6 * WSZ);

  const float* hcur = henc;
  float* louts[NL] = {lo0, lo1, lo2};
  for (int i = 0; i < NL; ++i) {
    k_aggregate<<<(NN + 3) / 4, 256, 0, stream>>>(
        (const float4*)hcur, rowptr, csr_src, csr_ea,
        edge_w + (size_t)i * 4 * DIM, edge_b + (size_t)i * DIM, (float4*)agg);
    k_mlp<<<RB64, 512, 0, stream>>>(
        hcur, agg, (const us8*)(wbh + i * WSZ), (const us8*)(wbl + i * WSZ),
        b1 + (size_t)i * DIM, (const us8*)(wbh + (3 + i) * WSZ),
        (const us8*)(wbl + (3 + i) * WSZ), b2 + (size_t)i * DIM, z2);
    dim3 gng(NG, DIM / 64);
    k_gnstats<<<gng, 256, 0, stream>>>(z2, gstart, gn_ms + (size_t)i * DIM,
                                       meanb, rstdb);
    k_gnapply<<<NN, 256, 0, stream>>>(z2, hcur, batch, meanb, rstdb,
                                      gn_ms + (size_t)i * DIM,
                                      gn_w + (size_t)i * DIM,
                                      gn_b + (size_t)i * DIM, louts[i]);
    hcur = louts[i];
  }

  k_jk_scores<<<RB64, 512, 0, stream>>>(lo0, lo1, lo2,
                                        (const us8*)(wbh + 6 * WSZ),
                                        (const us8*)(wbl + 6 * WSZ),
                                        attn_b1, attn_w2, scores);
  k_jk_pool<<<(NN + 31) / 32, 256, 0, stream>>>(lo0, lo1, lo2, scores, batch,
                                                pooled);
  k_final<<<NG, 128, 0, stream>>>(pooled, fc_w, fc_b, out);
}

// Round 14
// 1206.703 us; speedup vs baseline: 1.2043x; 1.2043x over previous
//
#include <hip/hip_runtime.h>

// Problem constants (match reference)
#define NN 50000     // nodes
#define NE 400000    // edges
#define NG 128       // graphs
#define DIM 256      // hidden
#define NL 3         // layers
#define OUTF 128
#define GN_EPS 1e-5f

typedef __attribute__((ext_vector_type(8))) __bf16 bf16x8;
typedef __attribute__((ext_vector_type(8))) unsigned short us8;
typedef __attribute__((ext_vector_type(4))) unsigned short us4;
typedef __attribute__((ext_vector_type(4))) float f32x4;

static __device__ __forceinline__ unsigned short f2bf(float f) {
  unsigned int u = __float_as_uint(f);
  unsigned int r = (u + 0x7fffu + ((u >> 16) & 1u)) >> 16;
  return (unsigned short)r;
}
static __device__ __forceinline__ float bf2f(unsigned short h) {
  return __uint_as_float(((unsigned int)h) << 16);
}
static __device__ __forceinline__ float fast_tanh(float x) {
  x = fminf(fmaxf(x, -15.f), 15.f);
  float e = __expf(2.f * x);
  return __fdividef(e - 1.f, e + 1.f);
}

// ---------------------------------------------------------------------------
__global__ __launch_bounds__(256) void k_encoder(
    const float* __restrict__ x, const float* __restrict__ w,
    const float* __restrict__ b, float* __restrict__ h) {
  int n = blockIdx.x, c = threadIdx.x;
  float x0 = x[n * 3 + 0], x1 = x[n * 3 + 1], x2 = x[n * 3 + 2];
  h[n * DIM + c] = b[c] + x0 * w[c] + x1 * w[DIM + c] + x2 * w[2 * DIM + c];
}

// ---------------------------------------------------------------------------
// CSR build
__global__ __launch_bounds__(256) void k_hist(const int* __restrict__ ei,
                                              int* __restrict__ cnt) {
  int e = blockIdx.x * 256 + threadIdx.x;
  if (e < NE) atomicAdd(&cnt[ei[NE + e]], 1);
}

__global__ __launch_bounds__(1024) void k_scan(const int* __restrict__ cnt,
                                               int* __restrict__ rowptr,
                                               int* __restrict__ cur) {
  __shared__ int ssum[1024];
  int t = threadIdx.x;
  const int CH = (NN + 1023) / 1024;
  int beg = t * CH, end = beg + CH;
  if (end > NN) end = NN;
  int s = 0;
  for (int i = beg; i < end; ++i) s += cnt[i];
  ssum[t] = s;
  __syncthreads();
  for (int off = 1; off < 1024; off <<= 1) {
    int v = (t >= off) ? ssum[t - off] : 0;
    __syncthreads();
    ssum[t] += v;
    __syncthreads();
  }
  int run = ssum[t] - s;
  for (int i = beg; i < end; ++i) {
    rowptr[i] = run;
    cur[i] = run;
    run += cnt[i];
  }
  if (t == 1023) rowptr[NN] = run;
}

__global__ __launch_bounds__(256) void k_scatter(
    const int* __restrict__ ei, const float4* __restrict__ ea,
    int* __restrict__ cur, int* __restrict__ csr_src,
    float4* __restrict__ csr_ea) {
  int e = blockIdx.x * 256 + threadIdx.x;
  if (e >= NE) return;
  int s = ei[e], d = ei[NE + e];
  int p = atomicAdd(&cur[d], 1);
  csr_src[p] = s;
  csr_ea[p] = ea[e];
}

__global__ __launch_bounds__(256) void k_gstart(const int* __restrict__ batch,
                                                int* __restrict__ gstart) {
  int n = blockIdx.x * 256 + threadIdx.x;
  if (n >= NN) return;
  int b = batch[n];
  int bp = (n == 0) ? -1 : batch[n - 1];
  for (int g = bp + 1; g <= b; ++g) gstart[g] = n;
  if (n == NN - 1)
    for (int g = b + 1; g <= NG; ++g) gstart[g] = NN;
}

// ---------------------------------------------------------------------------
// Weight prep: fp32 [K=256][N=256] -> MFMA B-fragment-ordered bf16 hi/lo.
// Fragment (nt*8+ks): lane l, elem j -> B[k][col], col=(nt<<4)+(l&15),
// k = ks*32 + 4*(l>>4) + 16*(j>>2) + (j&3)
__global__ __launch_bounds__(64) void k_prepw(const float* __restrict__ W,
                                              unsigned short* __restrict__ hi,
                                              unsigned short* __restrict__ lo) {
  int bt = blockIdx.x;  // nt*8 + ks
  int l = threadIdx.x;
  int col = ((bt >> 3) << 4) + (l & 15);
  int kb = ((bt & 7) << 5) + ((l >> 4) << 2);
  int base = (bt * 64 + l) * 8;
#pragma unroll
  for (int j = 0; j < 8; ++j) {
    int k = kb + ((j >> 2) << 4) + (j & 3);
    float w = W[k * DIM + col];
    unsigned short h = f2bf(w);
    hi[base + j] = h;
    lo[base + j] = f2bf(w - bf2f(h));
  }
}

// ---------------------------------------------------------------------------
// GINE aggregation, wave-per-node, 8-deep gather pipeline.
static __device__ __forceinline__ void edge_acc(
    float4& acc, float4 hv, float4 a, float4 wr0, float4 wr1, float4 wr2,
    float4 wr3, float4 bb) {
  float ex = fmaf(a.w, wr3.x, fmaf(a.z, wr2.x, fmaf(a.y, wr1.x, fmaf(a.x, wr0.x, bb.x))));
  float ey = fmaf(a.w, wr3.y, fmaf(a.z, wr2.y, fmaf(a.y, wr1.y, fmaf(a.x, wr0.y, bb.y))));
  float ez = fmaf(a.w, wr3.z, fmaf(a.z, wr2.z, fmaf(a.y, wr1.z, fmaf(a.x, wr0.z, bb.z))));
  float ew_ = fmaf(a.w, wr3.w, fmaf(a.z, wr2.w, fmaf(a.y, wr1.w, fmaf(a.x, wr0.w, bb.w))));
  acc.x += fmaxf(hv.x + ex, 0.f);
  acc.y += fmaxf(hv.y + ey, 0.f);
  acc.z += fmaxf(hv.z + ez, 0.f);
  acc.w += fmaxf(hv.w + ew_, 0.f);
}

__global__ __launch_bounds__(256) void k_aggregate(
    const float4* __restrict__ h4, const int* __restrict__ rowptr,
    const int* __restrict__ csr_src, const float4* __restrict__ csr_ea,
    const float* __restrict__ ew, const float* __restrict__ eb,
    float4* __restrict__ agg4) {
  const int lane = threadIdx.x & 63;
  const int n = (blockIdx.x << 2) + (threadIdx.x >> 6);
  if (n >= NN) return;
  const int c0 = lane << 2;
  const float4 wr0 = *(const float4*)(ew + c0);
  const float4 wr1 = *(const float4*)(ew + DIM + c0);
  const float4 wr2 = *(const float4*)(ew + 2 * DIM + c0);
  const float4 wr3 = *(const float4*)(ew + 3 * DIM + c0);
  const float4 bb = *(const float4*)(eb + c0);
  float4 acc = make_float4(0.f, 0.f, 0.f, 0.f);
  int j = rowptr[n];
  const int j1 = rowptr[n + 1];
  for (; j + 8 <= j1; j += 8) {
    int s[8];
    float4 a[8], hv[8];
#pragma unroll
    for (int u = 0; u < 8; ++u) s[u] = csr_src[j + u];
#pragma unroll
    for (int u = 0; u < 8; ++u) a[u] = csr_ea[j + u];
#pragma unroll
    for (int u = 0; u < 8; ++u) hv[u] = h4[(size_t)s[u] * 64 + lane];
#pragma unroll
    for (int u = 0; u < 8; ++u) edge_acc(acc, hv[u], a[u], wr0, wr1, wr2, wr3, bb);
  }
  for (; j + 2 <= j1; j += 2) {
    int s0 = csr_src[j], s1 = csr_src[j + 1];
    float4 a0 = csr_ea[j], a1 = csr_ea[j + 1];
    float4 h0 = h4[(size_t)s0 * 64 + lane];
    float4 h1 = h4[(size_t)s1 * 64 + lane];
    edge_acc(acc, h0, a0, wr0, wr1, wr2, wr3, bb);
    edge_acc(acc, h1, a1, wr0, wr1, wr2, wr3, bb);
  }
  for (; j < j1; ++j) {
    int s = csr_src[j];
    float4 a = csr_ea[j];
    float4 hv = h4[(size_t)s * 64 + lane];
    edge_acc(acc, hv, a, wr0, wr1, wr2, wr3, bb);
  }
  agg4[(size_t)n * 64 + lane] = acc;
}

// ---------------------------------------------------------------------------
// K-half-resident B: wave owns 2 nt-tiles (32 cols) but holds only 4 of 8
// ks fragments at a time -> B regs 64 VGPRs (was 128; the 128-reg version
// spilled at the compiler's 128-VGPR cap: rounds 5/10 showed 900 MB/dispatch
// scratch traffic).
static __device__ __forceinline__ void load_Bh(
    const us8* __restrict__ wh, const us8* __restrict__ wl, int w, int kh,
    int lane, us8 bh[4][2], us8 bl[4][2]) {
#pragma unroll
  for (int k4 = 0; k4 < 4; ++k4) {
#pragma unroll
    for (int t = 0; t < 2; ++t) {
      int nt = (w << 1) + t;
      int ks = (kh << 2) + k4;
      bh[k4][t] = wh[((nt << 3) + ks) * 64 + lane];
      bl[k4][t] = wl[((nt << 3) + ks) * 64 + lane];
    }
  }
}

// GEMM over one K-half: wave m-loops over all 4 row-tiles of the 64-row LDS
// A tile (bf16 hi/lo, XOR-swizzled row-major), B register-resident for this
// K-half. Same per-acc accumulation order as the full-K version (ks
// ascending) -> bitwise-identical results.
// acc[m][t] = C[m*16 + 4*(lane>>4) + q][((w*2+t)*16) + (lane&15)]
static __device__ __forceinline__ void gemm_half(
    const unsigned short* zh, const unsigned short* zl, const us8 bh[4][2],
    const us8 bl[4][2], int kh, int lane, f32x4 acc[4][2]) {
#pragma unroll
  for (int m = 0; m < 4; ++m) {
    const int arow = (m << 4) + (lane & 15);
    const int rx = arow & 7;
    const int rbase = arow << 8;
#pragma unroll
    for (int k4 = 0; k4 < 4; ++k4) {
      int ks = (kh << 2) + k4;
      int c0 = (ks << 5) + ((lane >> 4) << 2);
      int c1 = c0 + 16;
      int i0 = rbase + ((((c0 >> 3) ^ rx) << 3) | (c0 & 7));
      int i1 = rbase + ((((c1 >> 3) ^ rx) << 3) | (c1 & 7));
      us4 h0 = *(const us4*)(zh + i0), h1 = *(const us4*)(zh + i1);
      us4 l0 = *(const us4*)(zl + i0), l1 = *(const us4*)(zl + i1);
      us8 ahu = {h0.x, h0.y, h0.z, h0.w, h1.x, h1.y, h1.z, h1.w};
      us8 alu = {l0.x, l0.y, l0.z, l0.w, l1.x, l1.y, l1.z, l1.w};
      bf16x8 ah = __builtin_bit_cast(bf16x8, ahu);
      bf16x8 al = __builtin_bit_cast(bf16x8, alu);
#pragma unroll
      for (int t = 0; t < 2; ++t) {
        bf16x8 Bh = __builtin_bit_cast(bf16x8, bh[k4][t]);
        bf16x8 Bl = __builtin_bit_cast(bf16x8, bl[k4][t]);
        acc[m][t] = __builtin_amdgcn_mfma_f32_16x16x32_bf16(ah, Bh, acc[m][t], 0, 0, 0);
        acc[m][t] = __builtin_amdgcn_mfma_f32_16x16x32_bf16(al, Bh, acc[m][t], 0, 0, 0);
        acc[m][t] = __builtin_amdgcn_mfma_f32_16x16x32_bf16(ah, Bl, acc[m][t], 0, 0, 0);
      }
    }
  }
}

// full 256-K GEMM: two K-halves, B reloaded between them
static __device__ __forceinline__ void gemm_full(
    const unsigned short* zh, const unsigned short* zl,
    const us8* __restrict__ wh, const us8* __restrict__ wl, int w, int lane,
    f32x4 acc[4][2]) {
  us8 bh[4][2], bl[4][2];
  load_Bh(wh, wl, w, 0, lane, bh, bl);
  gemm_half(zh, zl, bh, bl, 0, lane, acc);
  load_Bh(wh, wl, w, 1, lane, bh, bl);
  gemm_half(zh, zl, bh, bl, 1, lane, acc);
}

// ---------------------------------------------------------------------------
// Fused MLP via MFMA, 512 threads (8 waves), 64-row tile.
// __launch_bounds__(512, 1): round-10 evidence showed (512,2) left the
// VGPR cap at 128 (LDS-occupancy-clamped heuristic / blocks-vs-waves arg
// ambiguity); "1" yields a >=256-VGPR budget under either interpretation.
__global__ __launch_bounds__(512, 1) void k_mlp(
    const float* __restrict__ h, const float* __restrict__ agg,
    const us8* __restrict__ w1h, const us8* __restrict__ w1l,
    const float* __restrict__ b1,
    const us8* __restrict__ w2h, const us8* __restrict__ w2l,
    const float* __restrict__ b2, float* __restrict__ z2out) {
  __shared__ unsigned short zh[64 * 256];
  __shared__ unsigned short zl[64 * 256];
  const int tid = threadIdx.x;
  const int m0 = blockIdx.x << 6;
  const int w = tid >> 6, lane = tid & 63;
  const int cl = lane & 15;

  // stage z = h + agg -> bf16 hi/lo, swizzled
  for (int i = tid; i < 4096; i += 512) {
    int r = i >> 6, c4 = i & 63;
    int n = m0 + r;
    float4 hv = make_float4(0.f, 0.f, 0.f, 0.f), av = hv;
    if (n < NN) {
      hv = *(const float4*)(h + (size_t)n * DIM + (c4 << 2));
      av = *(const float4*)(agg + (size_t)n * DIM + (c4 << 2));
    }
    float z0 = hv.x + av.x, z1 = hv.y + av.y, z2 = hv.z + av.z, z3 = hv.w + av.w;
    unsigned short h0 = f2bf(z0), h1 = f2bf(z1), h2 = f2bf(z2), h3 = f2bf(z3);
    us4 hq = {h0, h1, h2, h3};
    us4 lq = {f2bf(z0 - bf2f(h0)), f2bf(z1 - bf2f(h1)),
              f2bf(z2 - bf2f(h2)), f2bf(z3 - bf2f(h3))};
    int g = (c4 >> 1) ^ (r & 7);
    int idx = (r << 8) + (g << 3) + ((c4 & 1) << 2);
    *(us4*)(zh + idx) = hq;
    *(us4*)(zl + idx) = lq;
  }
  __syncthreads();

  f32x4 acc[4][2];
#pragma unroll
  for (int m = 0; m < 4; ++m) { acc[m][0] = {0.f,0.f,0.f,0.f}; acc[m][1] = {0.f,0.f,0.f,0.f}; }
  gemm_full(zh, zl, w1h, w1l, w, lane, acc);

  float bv1[2] = {b1[((w << 1) + 0) * 16 + cl], b1[((w << 1) + 1) * 16 + cl]};
  __syncthreads();  // all pass-1 reads of zh/zl done
#pragma unroll
  for (int m = 0; m < 4; ++m) {
#pragma unroll
    for (int t = 0; t < 2; ++t) {
      int col = ((w << 1) + t) * 16 + cl;
#pragma unroll
      for (int q = 0; q < 4; ++q) {
        float v = fmaxf(acc[m][t][q] + bv1[t], 0.f);
        unsigned short th = f2bf(v);
        unsigned short tl = f2bf(v - bf2f(th));
        int row = (m << 4) + ((lane >> 4) << 2) + q;
        int idx = (row << 8) + ((((col >> 3) ^ (row & 7)) << 3) | (col & 7));
        zh[idx] = th;
        zl[idx] = tl;
      }
    }
  }
  __syncthreads();

#pragma unroll
  for (int m = 0; m < 4; ++m) { acc[m][0] = {0.f,0.f,0.f,0.f}; acc[m][1] = {0.f,0.f,0.f,0.f}; }
  gemm_full(zh, zl, w2h, w2l, w, lane, acc);

  float bv2[2] = {b2[((w << 1) + 0) * 16 + cl], b2[((w << 1) + 1) * 16 + cl]};
#pragma unroll
  for (int m = 0; m < 4; ++m) {
#pragma unroll
    for (int t = 0; t < 2; ++t) {
      int col = ((w << 1) + t) * 16 + cl;
#pragma unroll
      for (int q = 0; q < 4; ++q) {
        int n = m0 + (m << 4) + ((lane >> 4) << 2) + q;
        if (n < NN)
          z2out[(size_t)n * DIM + col] = fmaxf(acc[m][t][q] + bv2[t], 0.f);
      }
    }
  }
}

// ---------------------------------------------------------------------------
// GraphNorm stats
__global__ __launch_bounds__(256) void k_gnstats(
    const float* __restrict__ z2, const int* __restrict__ gstart,
    const float* __restrict__ gms, float* __restrict__ meanb,
    float* __restrict__ rstdb) {
  __shared__ float red[4][64];
  int g = blockIdx.x;
  int cc = threadIdx.x & 63;
  int c = (blockIdx.y << 6) + cc;
  int ty = threadIdx.x >> 6;
  int s0 = gstart[g], s1 = gstart[g + 1];
  float cntf = fmaxf((float)(s1 - s0), 1.f);
  float s = 0.f;
  for (int n = s0 + ty; n < s1; n += 4) s += z2[(size_t)n * DIM + c];
  red[ty][cc] = s;
  __syncthreads();
  float mean = (red[0][cc] + red[1][cc] + red[2][cc] + red[3][cc]) / cntf;
  float a = mean * gms[c];
  float v = 0.f;
  for (int n = s0 + ty; n < s1; n += 4) {
    float d = z2[(size_t)n * DIM + c] - a;
    v = fmaf(d, d, v);
  }
  __syncthreads();
  red[ty][cc] = v;
  __syncthreads();
  if (ty == 0) {
    float var = (red[0][cc] + red[1][cc] + red[2][cc] + red[3][cc]) / cntf;
    meanb[(size_t)g * DIM + c] = mean;
    rstdb[(size_t)g * DIM + c] = rsqrtf(var + GN_EPS);
  }
}

__global__ __launch_bounds__(256) void k_gnapply(
    const float* __restrict__ z2, const float* __restrict__ hprev,
    const int* __restrict__ batch, const float* __restrict__ meanb,
    const float* __restrict__ rstdb, const float* __restrict__ gms,
    const float* __restrict__ gw, const float* __restrict__ gb,
    float* __restrict__ hout) {
  int n = blockIdx.x, c = threadIdx.x;
  int g = batch[n];
  float mean = meanb[g * DIM + c], rstd = rstdb[g * DIM + c];
  float sub = z2[n * DIM + c] - mean * gms[c];
  hout[n * DIM + c] = fmaf(gw[c] * sub, rstd, gb[c]) + hprev[n * DIM + c];
}

// ---------------------------------------------------------------------------
// JK scores, 512 threads; K-half-resident B, loops over the 3 layers.
__global__ __launch_bounds__(512, 1) void k_jk_scores(
    const float* __restrict__ lo0, const float* __restrict__ lo1,
    const float* __restrict__ lo2, const us8* __restrict__ wah,
    const us8* __restrict__ wal, const float* __restrict__ ab1,
    const float* __restrict__ aw2, float* __restrict__ scores) {
  __shared__ unsigned short zh[64 * 256];
  __shared__ unsigned short zl[64 * 256];
  __shared__ float sred[8][64];
  const int tid = threadIdx.x;
  const int m0 = blockIdx.x << 6;
  const int w = tid >> 6, lane = tid & 63;
  const int cl = lane & 15;

  float abv[2] = {ab1[((w << 1) + 0) * 16 + cl], ab1[((w << 1) + 1) * 16 + cl]};
  float awv[2] = {aw2[((w << 1) + 0) * 16 + cl], aw2[((w << 1) + 1) * 16 + cl]};

  const float* srcs[NL] = {lo0, lo1, lo2};
  for (int li = 0; li < NL; ++li) {
    const float* src = srcs[li];
    __syncthreads();  // previous iteration's reads done
    for (int i = tid; i < 4096; i += 512) {
      int r = i >> 6, c4 = i & 63;
      int n = m0 + r;
      float4 v = make_float4(0.f, 0.f, 0.f, 0.f);
      if (n < NN) v = *(const float4*)(src + (size_t)n * DIM + (c4 << 2));
      unsigned short h0 = f2bf(v.x), h1 = f2bf(v.y), h2 = f2bf(v.z), h3 = f2bf(v.w);
      us4 hq = {h0, h1, h2, h3};
      us4 lq = {f2bf(v.x - bf2f(h0)), f2bf(v.y - bf2f(h1)),
                f2bf(v.z - bf2f(h2)), f2bf(v.w - bf2f(h3))};
      int g = (c4 >> 1) ^ (r & 7);
      int idx = (r << 8) + (g << 3) + ((c4 & 1) << 2);
      *(us4*)(zh + idx) = hq;
      *(us4*)(zl + idx) = lq;
    }
    __syncthreads();

    f32x4 acc[4][2];
#pragma unroll
    for (int m = 0; m < 4; ++m) { acc[m][0] = {0.f,0.f,0.f,0.f}; acc[m][1] = {0.f,0.f,0.f,0.f}; }
    gemm_full(zh, zl, wah, wal, w, lane, acc);

    // per-row reduce: sum over this wave's 32 cols, then across waves via LDS
#pragma unroll
    for (int m = 0; m < 4; ++m) {
#pragma unroll
      for (int q = 0; q < 4; ++q) {
        float p = fast_tanh(acc[m][0][q] + abv[0]) * awv[0] +
                  fast_tanh(acc[m][1][q] + abv[1]) * awv[1];
        p += __shfl_xor(p, 1);
        p += __shfl_xor(p, 2);
        p += __shfl_xor(p, 4);
        p += __shfl_xor(p, 8);
        if (cl == 0) sred[w][(m << 4) + ((lane >> 4) << 2) + q] = p;
      }
    }
    __syncthreads();
    if (tid < 64) {
      float s = 0.f;
#pragma unroll
      for (int ww = 0; ww < 8; ++ww) s += sred[ww][tid];
      int n = m0 + tid;
      if (n < NN) scores[(size_t)n * NL + li] = s;
    }
  }
}

// JK softmax + weighted sum + global_add_pool
__global__ __launch_bounds__(256) void k_jk_pool(
    const float* __restrict__ lo0, const float* __restrict__ lo1,
    const float* __restrict__ lo2, const float* __restrict__ scores,
    const int* __restrict__ batch, float* __restrict__ pooled) {
  int m0 = blockIdx.x * 32, c = threadIdx.x;
  float acc = 0.f;
  int curg = -1;
  for (int r = 0; r < 32; ++r) {
    int n = m0 + r;
    if (n >= NN) break;
    int g = batch[n];
    if (g != curg) {
      if (curg >= 0) atomicAdd(&pooled[curg * DIM + c], acc);
      curg = g;
      acc = 0.f;
    }
    float s0 = scores[n * NL], s1 = scores[n * NL + 1], s2 = scores[n * NL + 2];
    float m = fmaxf(s0, fmaxf(s1, s2));
    float e0 = expf(s0 - m), e1 = expf(s1 - m), e2 = expf(s2 - m);
    float inv = 1.f / (e0 + e1 + e2);
    acc += (e0 * lo0[n * DIM + c] + e1 * lo1[n * DIM + c] +
            e2 * lo2[n * DIM + c]) * inv;
  }
  if (curg >= 0) atomicAdd(&pooled[curg * DIM + c], acc);
}

__global__ __launch_bounds__(128) void k_final(
    const float* __restrict__ pooled, const float* __restrict__ fw,
    const float* __restrict__ fb, float* __restrict__ out) {
  int g = blockIdx.x, o = threadIdx.x;
  float acc = fb[o];
  for (int k = 0; k < DIM; ++k)
    acc = fmaf(pooled[g * DIM + k], fw[k * OUTF + o], acc);
  out[g * OUTF + o] = acc;
}

// ---------------------------------------------------------------------------
extern "C" void kernel_launch(void* const* d_in, const int* in_sizes, int n_in,
                              void* d_out, int out_size, void* d_ws,
                              size_t ws_size, hipStream_t stream) {
  const float* x       = (const float*)d_in[0];
  const int*   ei      = (const int*)d_in[1];
  const float* eattr   = (const float*)d_in[2];
  const int*   batch   = (const int*)d_in[3];
  const float* enc_w   = (const float*)d_in[4];
  const float* enc_b   = (const float*)d_in[5];
  const float* edge_w  = (const float*)d_in[6];
  const float* edge_b  = (const float*)d_in[7];
  const float* w1      = (const float*)d_in[8];
  const float* b1      = (const float*)d_in[9];
  const float* w2      = (const float*)d_in[10];
  const float* b2      = (const float*)d_in[11];
  const float* gn_w    = (const float*)d_in[12];
  const float* gn_b    = (const float*)d_in[13];
  const float* gn_ms   = (const float*)d_in[14];
  const float* attn_w1 = (const float*)d_in[15];
  const float* attn_b1 = (const float*)d_in[16];
  const float* attn_w2 = (const float*)d_in[17];
  const float* fc_w    = (const float*)d_in[18];
  const float* fc_b    = (const float*)d_in[19];
  float* out = (float*)d_out;

  char* wsp = (char*)d_ws;
  auto alloc = [&](size_t bytes) {
    void* p = (void*)wsp;
    wsp += (bytes + 255) & ~(size_t)255;
    return p;
  };
  const size_t ND = (size_t)NN * DIM;
  const size_t WSZ = (size_t)DIM * DIM;
  float* henc   = (float*)alloc(ND * 4);
  float* lo0    = (float*)alloc(ND * 4);
  float* lo1    = (float*)alloc(ND * 4);
  float* lo2    = (float*)alloc(ND * 4);
  float* agg    = (float*)alloc(ND * 4);  // reused as z2 (row-safe alias)
  float* meanb  = (float*)alloc((size_t)NG * DIM * 4);
  float* rstdb  = (float*)alloc((size_t)NG * DIM * 4);
  float* scores = (float*)alloc((size_t)NN * NL * 4);
  float* pooled = (float*)alloc((size_t)NG * DIM * 4);
  int* rowptr   = (int*)alloc((size_t)(NN + 1) * 4);
  int* cur      = (int*)alloc((size_t)NN * 4);
  int* cnt      = (int*)alloc((size_t)NN * 4);
  int* gstart   = (int*)alloc((size_t)(NG + 1) * 4);
  int* csr_src  = (int*)alloc((size_t)NE * 4);
  float4* csr_ea = (float4*)alloc((size_t)NE * 16);
  unsigned short* wbh = (unsigned short*)alloc(7 * WSZ * 2);
  unsigned short* wbl = (unsigned short*)alloc(7 * WSZ * 2);

  float* z2 = agg;

  hipMemsetAsync(cnt, 0, (size_t)NN * 4, stream);
  hipMemsetAsync(pooled, 0, (size_t)NG * DIM * 4, stream);

  const int EB = (NE + 255) / 256;
  const int NB = (NN + 255) / 256;
  const int RB64 = (NN + 63) / 64;

  k_encoder<<<NN, 256, 0, stream>>>(x, enc_w, enc_b, henc);
  k_hist<<<EB, 256, 0, stream>>>(ei, cnt);
  k_scan<<<1, 1024, 0, stream>>>(cnt, rowptr, cur);
  k_scatter<<<EB, 256, 0, stream>>>(ei, (const float4*)eattr, cur, csr_src, csr_ea);
  k_gstart<<<NB, 256, 0, stream>>>(batch, gstart);

  for (int i = 0; i < NL; ++i) {
    k_prepw<<<128, 64, 0, stream>>>(w1 + i * WSZ, wbh + i * WSZ, wbl + i * WSZ);
    k_prepw<<<128, 64, 0, stream>>>(w2 + i * WSZ, wbh + (3 + i) * WSZ,
                                    wbl + (3 + i) * WSZ);
  }
  k_prepw<<<128, 64, 0, stream>>>(attn_w1, wbh + 6 * WSZ, wbl + 6 * WSZ);

  const float* hcur = henc;
  float* louts[NL] = {lo0, lo1, lo2};
  for (int i = 0; i < NL; ++i) {
    k_aggregate<<<(NN + 3) / 4, 256, 0, stream>>>(
        (const float4*)hcur, rowptr, csr_src, csr_ea,
        edge_w + (size_t)i * 4 * DIM, edge_b + (size_t)i * DIM, (float4*)agg);
    k_mlp<<<RB64, 512, 0, stream>>>(
        hcur, agg, (const us8*)(wbh + i * WSZ), (const us8*)(wbl + i * WSZ),
        b1 + (size_t)i * DIM, (const us8*)(wbh + (3 + i) * WSZ),
        (const us8*)(wbl + (3 + i) * WSZ), b2 + (size_t)i * DIM, z2);
    dim3 gng(NG, DIM / 64);
    k_gnstats<<<gng, 256, 0, stream>>>(z2, gstart, gn_ms + (size_t)i * DIM,
                                       meanb, rstdb);
    k_gnapply<<<NN, 256, 0, stream>>>(z2, hcur, batch, meanb, rstdb,
                                      gn_ms + (size_t)i * DIM,
                                      gn_w + (size_t)i * DIM,
                                      gn_b + (size_t)i * DIM, louts[i]);
    hcur = louts[i];
  }

  k_jk_scores<<<RB64, 512, 0, stream>>>(lo0, lo1, lo2,
                                        (const us8*)(wbh + 6 * WSZ),
                                        (const us8*)(wbl + 6 * WSZ),
                                        attn_b1, attn_w2, scores);
  k_jk_pool<<<(NN + 31) / 32, 256, 0, stream>>>(lo0, lo1, lo2, scores, batch,
                                                pooled);
  k_final<<<NG, 128, 0, stream>>>(pooled, fc_w, fc_b, out);
}